// Round 1
// baseline (287.802 us; speedup 1.0000x reference)
//
#include <hip/hip_runtime.h>

#define BATCH 2
#define SEQ   4096
#define HID   256
#define NHEAD 8
#define DH    32

typedef __attribute__((ext_vector_type(8))) _Float16 half8;
typedef __attribute__((ext_vector_type(4))) _Float16 half4;
typedef __attribute__((ext_vector_type(4))) float    f32x4;

// ---------------------------------------------------------------- convert
__global__ void cvt_f32_f16(const float* __restrict__ src,
                            _Float16* __restrict__ dst, int n) {
    int i = (blockIdx.x * blockDim.x + threadIdx.x) * 4;
    if (i >= n) return;
    f32x4 v = *reinterpret_cast<const f32x4*>(src + i);
    half4 h;
#pragma unroll
    for (int c = 0; c < 4; ++c) h[c] = (_Float16)v[c];
    *reinterpret_cast<half4*>(dst + i) = h;
}

// ---------------------------------------------------------------- QKV proj
// out = x @ W^T (+bias). Q scaled by 1/sqrt(DH), stored [B][H][N][DH].
// K stored [B][H][N][DH]. V stored transposed [B][H][DH][N].
__global__ __launch_bounds__(256) void qkv_proj(
    const _Float16* __restrict__ xh, const _Float16* __restrict__ Wh,
    const float* __restrict__ bq, const float* __restrict__ bk,
    const float* __restrict__ bv,
    _Float16* __restrict__ Qh, _Float16* __restrict__ Kh,
    _Float16* __restrict__ Vt)
{
    const int z   = blockIdx.z;
    const int m0  = blockIdx.x * 64;
    const int n0  = blockIdx.y * 64;
    const int tid = threadIdx.x;
    const int w   = tid >> 6, lane = tid & 63;
    const int lr  = lane & 15, lg = lane >> 4;
    const int wr  = (w >> 1) * 32, wc = (w & 1) * 32;

    const _Float16* Wp = Wh + (size_t)z * HID * HID;
    const float* bias = (z == 0) ? bq : (z == 1) ? bk : bv;

    f32x4 acc[2][2] = {};
    const int ar = m0 + wr + lr;
    const int br = n0 + wc + lr;
#pragma unroll
    for (int ks = 0; ks < 8; ++ks) {
        const int ko = ks * 32 + lg * 8;
        half8 a0 = *reinterpret_cast<const half8*>(xh + (size_t)ar * HID + ko);
        half8 a1 = *reinterpret_cast<const half8*>(xh + (size_t)(ar + 16) * HID + ko);
        half8 b0 = *reinterpret_cast<const half8*>(Wp + (size_t)br * HID + ko);
        half8 b1 = *reinterpret_cast<const half8*>(Wp + (size_t)(br + 16) * HID + ko);
        acc[0][0] = __builtin_amdgcn_mfma_f32_16x16x32_f16(a0, b0, acc[0][0], 0, 0, 0);
        acc[0][1] = __builtin_amdgcn_mfma_f32_16x16x32_f16(a0, b1, acc[0][1], 0, 0, 0);
        acc[1][0] = __builtin_amdgcn_mfma_f32_16x16x32_f16(a1, b0, acc[1][0], 0, 0, 0);
        acc[1][1] = __builtin_amdgcn_mfma_f32_16x16x32_f16(a1, b1, acc[1][1], 0, 0, 0);
    }
#pragma unroll
    for (int mf = 0; mf < 2; ++mf)
#pragma unroll
    for (int nf = 0; nf < 2; ++nf)
#pragma unroll
    for (int r = 0; r < 4; ++r) {
        const int m  = m0 + wr + mf * 16 + lg * 4 + r;
        const int o  = n0 + wc + nf * 16 + lr;
        const int bb = m >> 12, nn = m & (SEQ - 1);
        const int hh = o >> 5,  dd = o & (DH - 1);
        float v = acc[mf][nf][r] + bias[o];
        if (z == 0) {
            Qh[(((size_t)(bb * NHEAD + hh) * SEQ) + nn) * DH + dd] =
                (_Float16)(v * 0.17677669529663687f);
        } else if (z == 1) {
            Kh[(((size_t)(bb * NHEAD + hh) * SEQ) + nn) * DH + dd] = (_Float16)v;
        } else {
            Vt[(((size_t)(bb * NHEAD + hh) * DH) + dd) * SEQ + nn] = (_Float16)v;
        }
    }
}

// ---------------------------------------------------------------- attention
// grid (SEQ/32, BATCH), 512 threads = 8 waves, wave w == head w.
// i-tile 32 rows, j-tiles of 64, online softmax. Distance bias computed
// once per block into LDS, shared by all 8 heads.
__global__ __launch_bounds__(512) void attn_kernel(
    const _Float16* __restrict__ Qh, const _Float16* __restrict__ Kh,
    const _Float16* __restrict__ Vt, const float* __restrict__ pos,
    _Float16* __restrict__ AO)
{
    __shared__ __align__(16) float pi[32][4];
    __shared__ __align__(16) float pj[64][4];
    __shared__ __align__(16) float sbias[32][68];
    __shared__ __align__(16) _Float16 Pl[NHEAD][2048];  // 4KB per wave, XOR-swizzled

    const int b   = blockIdx.y;
    const int i0  = blockIdx.x * 32;
    const int tid = threadIdx.x;
    const int h   = tid >> 6;
    const int lane = tid & 63;
    const int lr  = lane & 15, lg = lane >> 4;

    if (tid < 32) {
        const float* p = pos + (size_t)(b * SEQ + i0 + tid) * 3;
        float x = p[0], y = p[1], zz = p[2];
        pi[tid][0] = x; pi[tid][1] = y; pi[tid][2] = zz;
        pi[tid][3] = x * x + y * y + zz * zz;
    }

    const _Float16* Qbase = Qh + ((size_t)(b * NHEAD + h) * SEQ + i0) * DH;
    const _Float16* Kbase = Kh + (size_t)(b * NHEAD + h) * SEQ * DH;
    const _Float16* Vbase = Vt + (size_t)(b * NHEAD + h) * DH * SEQ;

    const half8 aq0 = *reinterpret_cast<const half8*>(Qbase + (size_t)lr * DH + lg * 8);
    const half8 aq1 = *reinterpret_cast<const half8*>(Qbase + (size_t)(16 + lr) * DH + lg * 8);

    f32x4 acc[2][2] = {};
    float mrun[2][4], lrun[2][4];
#pragma unroll
    for (int mf = 0; mf < 2; ++mf)
#pragma unroll
    for (int r = 0; r < 4; ++r) { mrun[mf][r] = -__builtin_inff(); lrun[mf][r] = 0.f; }

    char* Pbytes = (char*)&Pl[h][0];

    for (int jt = 0; jt < SEQ / 64; ++jt) {
        const int j0 = jt * 64;
        __syncthreads();   // protect pj/sbias reuse
        if (tid < 64) {
            const float* p = pos + (size_t)(b * SEQ + j0 + tid) * 3;
            float x = p[0], y = p[1], zz = p[2];
            pj[tid][0] = x; pj[tid][1] = y; pj[tid][2] = zz;
            pj[tid][3] = x * x + y * y + zz * zz;
        }
        __syncthreads();
        {   // bias tile 32x64: 4 elements per thread
            const int row = tid >> 4, c0 = (tid & 15) * 4;
            const float xi = pi[row][0], yi = pi[row][1], zi = pi[row][2], si = pi[row][3];
            f32x4 bb;
#pragma unroll
            for (int c = 0; c < 4; ++c) {
                const int col = c0 + c;
                float dot = xi * pj[col][0] + yi * pj[col][1] + zi * pj[col][2];
                float d2  = si + pj[col][3] - 2.f * dot;
                bb[c] = -0.1f * sqrtf(fmaxf(d2, 0.f));
            }
            *reinterpret_cast<f32x4*>(&sbias[row][c0]) = bb;
        }
        __syncthreads();

        // ---- S = Q K^T  (Q pre-scaled by 1/sqrt(DH))
        half8 bk8[4];
#pragma unroll
        for (int cf = 0; cf < 4; ++cf)
            bk8[cf] = *reinterpret_cast<const half8*>(
                Kbase + (size_t)(j0 + cf * 16 + lr) * DH + lg * 8);
        f32x4 s[2][4];
#pragma unroll
        for (int mf = 0; mf < 2; ++mf)
#pragma unroll
        for (int cf = 0; cf < 4; ++cf) {
            f32x4 zero = {};
            s[mf][cf] = __builtin_amdgcn_mfma_f32_16x16x32_f16(
                mf ? aq1 : aq0, bk8[cf], zero, 0, 0, 0);
        }

        // ---- bias add + online softmax (rows live in 16-lane groups)
#pragma unroll
        for (int mf = 0; mf < 2; ++mf)
#pragma unroll
        for (int r = 0; r < 4; ++r) {
            const int row = mf * 16 + lg * 4 + r;
            float v[4];
#pragma unroll
            for (int c = 0; c < 4; ++c) v[c] = s[mf][c][r] + sbias[row][c * 16 + lr];
            float tmax = fmaxf(fmaxf(v[0], v[1]), fmaxf(v[2], v[3]));
#pragma unroll
            for (int msk = 8; msk >= 1; msk >>= 1)
                tmax = fmaxf(tmax, __shfl_xor(tmax, msk, 64));
            const float mold = mrun[mf][r];
            const float mnew = fmaxf(mold, tmax);
            const float alpha = __expf(mold - mnew);
            float rsum = 0.f;
#pragma unroll
            for (int c = 0; c < 4; ++c) { v[c] = __expf(v[c] - mnew); rsum += v[c]; }
#pragma unroll
            for (int msk = 8; msk >= 1; msk >>= 1)
                rsum += __shfl_xor(rsum, msk, 64);
            lrun[mf][r] = lrun[mf][r] * alpha + rsum;
            mrun[mf][r] = mnew;
            acc[mf][0][r] *= alpha;
            acc[mf][1][r] *= alpha;
#pragma unroll
            for (int c = 0; c < 4; ++c) {
                const int col = c * 16 + lr;
                const int off = (row * 128 + col * 2) ^ ((row & 7) << 4);
                *reinterpret_cast<_Float16*>(Pbytes + off) = (_Float16)v[c];
            }
        }

        // ---- PV: acc += P(32x64) @ V(64x32); wave-private P, no barrier
#pragma unroll
        for (int ks = 0; ks < 2; ++ks) {
            half8 bv0 = *reinterpret_cast<const half8*>(
                Vbase + (size_t)lr * SEQ + j0 + ks * 32 + lg * 8);
            half8 bv1 = *reinterpret_cast<const half8*>(
                Vbase + (size_t)(16 + lr) * SEQ + j0 + ks * 32 + lg * 8);
#pragma unroll
            for (int mf = 0; mf < 2; ++mf) {
                const int prow = mf * 16 + lr;
                const int poff = (prow * 128 + (ks * 32 + lg * 8) * 2) ^ ((prow & 7) << 4);
                half8 pa = *reinterpret_cast<const half8*>(Pbytes + poff);
                acc[mf][0] = __builtin_amdgcn_mfma_f32_16x16x32_f16(pa, bv0, acc[mf][0], 0, 0, 0);
                acc[mf][1] = __builtin_amdgcn_mfma_f32_16x16x32_f16(pa, bv1, acc[mf][1], 0, 0, 0);
            }
        }
    }

    // ---- epilogue: divide by row sums, store AO[b][n][h*32+d]
#pragma unroll
    for (int mf = 0; mf < 2; ++mf)
#pragma unroll
    for (int r = 0; r < 4; ++r) {
        const float inv = 1.f / lrun[mf][r];
        const int row = mf * 16 + lg * 4 + r;
#pragma unroll
        for (int df = 0; df < 2; ++df) {
            AO[((size_t)(b * SEQ + i0 + row)) * HID + h * DH + df * 16 + lr] =
                (_Float16)(acc[mf][df][r] * inv);
        }
    }
}

// ---------------------------------------------------------------- out proj
__global__ __launch_bounds__(256) void out_proj(
    const _Float16* __restrict__ AO, const _Float16* __restrict__ Woh,
    const float* __restrict__ bo, float* __restrict__ out)
{
    const int m0  = blockIdx.x * 64;
    const int n0  = blockIdx.y * 64;
    const int tid = threadIdx.x;
    const int w   = tid >> 6, lane = tid & 63;
    const int lr  = lane & 15, lg = lane >> 4;
    const int wr  = (w >> 1) * 32, wc = (w & 1) * 32;

    f32x4 acc[2][2] = {};
    const int ar = m0 + wr + lr;
    const int br = n0 + wc + lr;
#pragma unroll
    for (int ks = 0; ks < 8; ++ks) {
        const int ko = ks * 32 + lg * 8;
        half8 a0 = *reinterpret_cast<const half8*>(AO + (size_t)ar * HID + ko);
        half8 a1 = *reinterpret_cast<const half8*>(AO + (size_t)(ar + 16) * HID + ko);
        half8 b0 = *reinterpret_cast<const half8*>(Woh + (size_t)br * HID + ko);
        half8 b1 = *reinterpret_cast<const half8*>(Woh + (size_t)(br + 16) * HID + ko);
        acc[0][0] = __builtin_amdgcn_mfma_f32_16x16x32_f16(a0, b0, acc[0][0], 0, 0, 0);
        acc[0][1] = __builtin_amdgcn_mfma_f32_16x16x32_f16(a0, b1, acc[0][1], 0, 0, 0);
        acc[1][0] = __builtin_amdgcn_mfma_f32_16x16x32_f16(a1, b0, acc[1][0], 0, 0, 0);
        acc[1][1] = __builtin_amdgcn_mfma_f32_16x16x32_f16(a1, b1, acc[1][1], 0, 0, 0);
    }
#pragma unroll
    for (int mf = 0; mf < 2; ++mf)
#pragma unroll
    for (int nf = 0; nf < 2; ++nf)
#pragma unroll
    for (int r = 0; r < 4; ++r) {
        const int m = m0 + wr + mf * 16 + lg * 4 + r;
        const int o = n0 + wc + nf * 16 + lr;
        out[(size_t)m * HID + o] = acc[mf][nf][r] + bo[o];
    }
}

// ---------------------------------------------------------------- launch
extern "C" void kernel_launch(void* const* d_in, const int* in_sizes, int n_in,
                              void* d_out, int out_size, void* d_ws, size_t ws_size,
                              hipStream_t stream)
{
    const float* x   = (const float*)d_in[0];
    const float* pos = (const float*)d_in[1];
    const float* Wq  = (const float*)d_in[2];
    const float* bq  = (const float*)d_in[3];
    const float* Wk  = (const float*)d_in[4];
    const float* bk  = (const float*)d_in[5];
    const float* Wv  = (const float*)d_in[6];
    const float* bv  = (const float*)d_in[7];
    const float* Wo  = (const float*)d_in[8];
    const float* bo  = (const float*)d_in[9];
    float* out = (float*)d_out;

    char* ws = (char*)d_ws;
    _Float16* Qh = (_Float16*)(ws);                 // 4 MB
    _Float16* Kh = (_Float16*)(ws + (4  << 20));    // 4 MB
    _Float16* Vt = (_Float16*)(ws + (8  << 20));    // 4 MB
    _Float16* xh = (_Float16*)(ws + (12 << 20));    // 4 MB (reused as AO)
    _Float16* AO = xh;                              // safe: attn runs after qkv_proj
    _Float16* Wh = (_Float16*)(ws + (16 << 20));    // 512 KB

    const int NX = BATCH * SEQ * HID;               // 2,097,152
    const int NW = HID * HID;                       // 65,536
    cvt_f32_f16<<<NX / 1024, 256, 0, stream>>>(x,  xh, NX);
    cvt_f32_f16<<<NW / 1024, 256, 0, stream>>>(Wq, Wh + 0 * NW, NW);
    cvt_f32_f16<<<NW / 1024, 256, 0, stream>>>(Wk, Wh + 1 * NW, NW);
    cvt_f32_f16<<<NW / 1024, 256, 0, stream>>>(Wv, Wh + 2 * NW, NW);
    cvt_f32_f16<<<NW / 1024, 256, 0, stream>>>(Wo, Wh + 3 * NW, NW);

    qkv_proj<<<dim3(BATCH * SEQ / 64, HID / 64, 3), 256, 0, stream>>>(
        xh, Wh, bq, bk, bv, Qh, Kh, Vt);

    attn_kernel<<<dim3(SEQ / 32, BATCH), 512, 0, stream>>>(Qh, Kh, Vt, pos, AO);

    out_proj<<<dim3(BATCH * SEQ / 64, HID / 64), 256, 0, stream>>>(
        AO, Wh + 3 * NW, bo, out);
}